// Round 5
// baseline (287.138 us; speedup 1.0000x reference)
//
#include <hip/hip_runtime.h>
#include <hip/hip_bf16.h>
#include <math.h>

typedef __bf16 bf16x4 __attribute__((ext_vector_type(4)));
typedef __bf16 bf16x8 __attribute__((ext_vector_type(8)));
typedef float f32x4 __attribute__((ext_vector_type(4)));

#define MFMA16(a, b, c) __builtin_amdgcn_mfma_f32_16x16x32_bf16(a, b, c, 0, 0, 0)
#define QSCALE 0.1803368801111204f  // 0.125 * log2(e): folded into W's Q-columns

// async global->LDS, 16B/lane, dest = wave-uniform base + lane*16
__device__ __forceinline__ void gload_lds16(const __bf16* g, __bf16* l) {
  __builtin_amdgcn_global_load_lds((const __attribute__((address_space(1))) void*)g,
                                   (__attribute__((address_space(3))) void*)l,
                                   16, 0, 0);
}

// ---------------------------------------------------------------------------
// Kernel 0: convert X fp32 -> bf16
// ---------------------------------------------------------------------------
__global__ __launch_bounds__(256) void convert_x(const float* __restrict__ in,
                                                 __bf16* __restrict__ out) {
  int i = blockIdx.x * 256 + threadIdx.x;
  float4 v = ((const float4*)in)[i];
  bf16x4 o = {(__bf16)v.x, (__bf16)v.y, (__bf16)v.z, (__bf16)v.w};
  *(bf16x4*)&out[i * 4] = o;
}

// ---------------------------------------------------------------------------
// Kernel 1: transpose+convert W fp32 [1024,3072] -> Wt bf16 [3072,1024].
//   Q output-features (n<1024, i.e. bx<16) pre-scaled by 0.125*log2(e) so the
//   attention softmax is a bare v_exp_f32.
// ---------------------------------------------------------------------------
__global__ __launch_bounds__(256) void transpose_w(const float* __restrict__ W,
                                                   __bf16* __restrict__ Wt) {
  __shared__ __bf16 tile[64][65];
  const int bx = blockIdx.x;
  const int by = blockIdx.y;
  const int t = threadIdx.x;
  const int lr = t >> 6;
  const int lc = t & 63;
  const float sc = (bx < 16) ? QSCALE : 1.0f;  // block-uniform
#pragma unroll
  for (int i = 0; i < 16; ++i) {
    int r = lr + i * 4;
    tile[r][lc] = (__bf16)(W[(size_t)(by * 64 + r) * 3072 + bx * 64 + lc] * sc);
  }
  __syncthreads();
#pragma unroll
  for (int i = 0; i < 16; ++i) {
    int r = lr + i * 4;
    Wt[(size_t)(bx * 64 + r) * 1024 + by * 64 + lc] = tile[lc][r];
  }
}

// ---------------------------------------------------------------------------
// Kernel 2: QKV = X @ W. 128x128 tile, BK=32, global_load_lds width=16
//   (m97 ladder structure: unpadded LDS [row][32], 2-barrier K-loop).
// ---------------------------------------------------------------------------
__global__ __launch_bounds__(256) void gemm_qkv(const __bf16* __restrict__ X,
                                                const __bf16* __restrict__ Wt,
                                                __bf16* __restrict__ QKV) {
  __shared__ __bf16 As[128 * 32];
  __shared__ __bf16 Bs[128 * 32];
  const int t = threadIdx.x;
  const int lane = t & 63;
  const int wave = t >> 6;
  const int quad = lane >> 4;
  const int l16 = lane & 15;
  const int n0 = blockIdx.x * 128;
  const int m0 = blockIdx.y * 128;
  const int wm = (wave & 1) * 64;
  const int wn = (wave >> 1) * 64;

  // staging: lane i of wave w covers row w*16 + (i>>2), cols (i&3)*8 .. +7
  const __bf16* Ag = &X[(size_t)(m0 + wave * 16 + (lane >> 2)) * 1024 + (lane & 3) * 8];
  const __bf16* Bg = &Wt[(size_t)(n0 + wave * 16 + (lane >> 2)) * 1024 + (lane & 3) * 8];
  __bf16* As0 = &As[wave * 512];         // rows w*16..w*16+15
  __bf16* As1 = &As[2048 + wave * 512];  // rows 64+w*16..
  __bf16* Bs0 = &Bs[wave * 512];
  __bf16* Bs1 = &Bs[2048 + wave * 512];

  f32x4 acc[4][4] = {};

  for (int k0 = 0; k0 < 1024; k0 += 32) {
    gload_lds16(Ag + k0, As0);
    gload_lds16(Ag + (size_t)64 * 1024 + k0, As1);
    gload_lds16(Bg + k0, Bs0);
    gload_lds16(Bg + (size_t)64 * 1024 + k0, Bs1);
    __syncthreads();  // drains vmcnt: staged tile visible

    bf16x8 af[4], bf[4];
#pragma unroll
    for (int mi = 0; mi < 4; ++mi)
      af[mi] = *(const bf16x8*)&As[(wm + mi * 16 + l16) * 32 + quad * 8];
#pragma unroll
    for (int ni = 0; ni < 4; ++ni)
      bf[ni] = *(const bf16x8*)&Bs[(wn + ni * 16 + l16) * 32 + quad * 8];
#pragma unroll
    for (int mi = 0; mi < 4; ++mi)
#pragma unroll
      for (int ni = 0; ni < 4; ++ni)
        acc[mi][ni] = MFMA16(af[mi], bf[ni], acc[mi][ni]);
    __syncthreads();  // all reads done before next overwrite
  }

#pragma unroll
  for (int mi = 0; mi < 4; ++mi)
#pragma unroll
    for (int ni = 0; ni < 4; ++ni)
#pragma unroll
      for (int r = 0; r < 4; ++r) {
        int row = m0 + wm + mi * 16 + quad * 4 + r;
        int col = n0 + wn + ni * 16 + l16;
        QKV[(size_t)row * 3072 + col] = (__bf16)acc[mi][ni][r];
      }
}

// ---------------------------------------------------------------------------
// Kernel 3: transpose V part of QKV -> Vt [b*16+h][d=64][key=2048]  bf16
// ---------------------------------------------------------------------------
__global__ __launch_bounds__(256) void transpose_v(const __bf16* __restrict__ QKV,
                                                   __bf16* __restrict__ Vt) {
  __shared__ __bf16 tile[64][65];
  const int k0 = blockIdx.x * 64;
  const int h = blockIdx.y;
  const int b = blockIdx.z;
  const int t = threadIdx.x;
  const int lr = t >> 6;
  const int lc = t & 63;
  const __bf16* src = QKV + (size_t)b * 2048 * 3072 + 2048 + h * 64;
  __bf16* dst = Vt + (size_t)(b * 16 + h) * 64 * 2048;
#pragma unroll
  for (int i = 0; i < 16; ++i) {
    int r = lr + i * 4;
    tile[r][lc] = src[(size_t)(k0 + r) * 3072 + lc];
  }
  __syncthreads();
#pragma unroll
  for (int i = 0; i < 16; ++i) {
    int d = lr + i * 4;
    dst[(size_t)d * 2048 + k0 + lc] = tile[lc][d];
  }
}

// ---------------------------------------------------------------------------
// Kernel 4: flash attention. 64 q-rows per wave (256/block), LDS-staged K/V,
//   S^T = K.Q^T, bare-exp2 softmax (scale pre-folded into Q), P via
//   wave-private LDS round-trip, denominator reduced once at the end.
// ---------------------------------------------------------------------------
#define AT_LD 72  // 144B rows: 16B-aligned, fragment reads 2-way alias = free

__global__ __launch_bounds__(256) void attn(const __bf16* __restrict__ QKV,
                                            const __bf16* __restrict__ Vt,
                                            float* __restrict__ Out) {
  const int h = blockIdx.y;
  const int b = blockIdx.z;
  const int t = threadIdx.x;
  const int lane = t & 63;
  const int wave = t >> 6;
  const int quad = lane >> 4;
  const int l16 = lane & 15;
  const int q0w = blockIdx.x * 256 + wave * 64;

  const size_t base = (size_t)b * 2048 * 3072;
  const __bf16* Qb = QKV + base + h * 64;
  const __bf16* Kb = QKV + base + 1024 + h * 64;
  const __bf16* Vtb = Vt + (size_t)(b * 16 + h) * 64 * 2048;  // [d][key]

  __shared__ __bf16 Ks[64 * AT_LD];     // [key][d]
  __shared__ __bf16 Vs[64 * AT_LD];     // [d][key]
  __shared__ __bf16 Ps[4][64 * AT_LD];  // wave-private [q][key]
  __bf16* Psw = Ps[wave];

  // Q fragments: lane holds Q[q=mi*16+l16][d=kc*32+quad*8+j]  (pre-scaled)
  bf16x8 qf[4][2];
#pragma unroll
  for (int mi = 0; mi < 4; ++mi)
#pragma unroll
    for (int kc = 0; kc < 2; ++kc)
      qf[mi][kc] = *(const bf16x8*)&Qb[(size_t)(q0w + mi * 16 + l16) * 3072 + kc * 32 + quad * 8];

  f32x4 o[4][4] = {};
  float lsum[4] = {0.0f, 0.0f, 0.0f, 0.0f};

  const int srow = t >> 2;      // staging row 0..63
  const int sc = (t & 3) * 16;  // staging col chunk

  for (int kv0 = 0; kv0 < 2048; kv0 += 64) {
    // ---- stage K [key][d] and V [d][key] (coalesced, reg round-trip) ----
    bf16x8 k0v = *(const bf16x8*)&Kb[(size_t)(kv0 + srow) * 3072 + sc];
    bf16x8 k1v = *(const bf16x8*)&Kb[(size_t)(kv0 + srow) * 3072 + sc + 8];
    bf16x8 v0v = *(const bf16x8*)&Vtb[(size_t)srow * 2048 + kv0 + sc];
    bf16x8 v1v = *(const bf16x8*)&Vtb[(size_t)srow * 2048 + kv0 + sc + 8];
    __syncthreads();  // prior tile's fragment reads done
    *(bf16x8*)&Ks[srow * AT_LD + sc] = k0v;
    *(bf16x8*)&Ks[srow * AT_LD + sc + 8] = k1v;
    *(bf16x8*)&Vs[srow * AT_LD + sc] = v0v;
    *(bf16x8*)&Vs[srow * AT_LD + sc + 8] = v1v;
    __syncthreads();

    // ---- per key-tile mt: S^T = K.Q^T then immediate exp2 + P stash ----
#pragma unroll
    for (int mt = 0; mt < 4; ++mt) {
      bf16x8 kf0 = *(const bf16x8*)&Ks[(mt * 16 + l16) * AT_LD + quad * 8];
      bf16x8 kf1 = *(const bf16x8*)&Ks[(mt * 16 + l16) * AT_LD + 32 + quad * 8];
      f32x4 stt[4];
#pragma unroll
      for (int mi = 0; mi < 4; ++mi) {
        f32x4 z = {};
        z = MFMA16(kf0, qf[mi][0], z);
        z = MFMA16(kf1, qf[mi][1], z);
        stt[mi] = z;
      }
      // lane owns (q=l16, keys mt*16+quad*4+r); p = 2^s == e^(qk/8)
#pragma unroll
      for (int mi = 0; mi < 4; ++mi) {
        bf16x4 pk;
#pragma unroll
        for (int r = 0; r < 4; ++r) {
          float p = __builtin_amdgcn_exp2f(stt[mi][r]);
          lsum[mi] += p;
          pk[r] = (__bf16)p;
        }
        *(bf16x4*)&Psw[(mi * 16 + l16) * AT_LD + mt * 16 + quad * 4] = pk;
      }
    }

    // ---- P A-fragments (wave-local, lgkmcnt-only dependency) ----
    bf16x8 pf[4][2];
#pragma unroll
    for (int mi = 0; mi < 4; ++mi)
#pragma unroll
      for (int kc = 0; kc < 2; ++kc)
        pf[mi][kc] = *(const bf16x8*)&Psw[(mi * 16 + l16) * AT_LD + kc * 32 + quad * 8];

    // ---- O += P V : 64q x 64d ----
#pragma unroll
    for (int dt = 0; dt < 4; ++dt) {
      bf16x8 vf0 = *(const bf16x8*)&Vs[(dt * 16 + l16) * AT_LD + quad * 8];
      bf16x8 vf1 = *(const bf16x8*)&Vs[(dt * 16 + l16) * AT_LD + 32 + quad * 8];
#pragma unroll
      for (int mi = 0; mi < 4; ++mi) {
        o[mi][dt] = MFMA16(pf[mi][0], vf0, o[mi][dt]);
        o[mi][dt] = MFMA16(pf[mi][1], vf1, o[mi][dt]);
      }
    }
  }

  // ---- denominator: combine the 4 quads' key-partitions ----
#pragma unroll
  for (int mi = 0; mi < 4; ++mi) {
    lsum[mi] += __shfl_xor(lsum[mi], 16);
    lsum[mi] += __shfl_xor(lsum[mi], 32);
  }

  // ---- epilogue ----
#pragma unroll
  for (int mi = 0; mi < 4; ++mi)
#pragma unroll
    for (int r = 0; r < 4; ++r) {
      float inv = 1.0f / __shfl(lsum[mi], quad * 4 + r);
      int orow = b * 2048 + q0w + mi * 16 + quad * 4 + r;
#pragma unroll
      for (int dt = 0; dt < 4; ++dt)
        Out[(size_t)orow * 1024 + h * 64 + dt * 16 + l16] = o[mi][dt][r] * inv;
    }
}

// ---------------------------------------------------------------------------
extern "C" void kernel_launch(void* const* d_in, const int* in_sizes, int n_in,
                              void* d_out, int out_size, void* d_ws, size_t ws_size,
                              hipStream_t stream) {
  const float* x = (const float*)d_in[0];        // [4,2048,1024] fp32
  const float* w = (const float*)d_in[1];        // [1024,3072]  fp32
  float* out = (float*)d_out;                    // [4,2048,1024] fp32

  __bf16* Wt = (__bf16*)d_ws;                    // [3072,1024]   6.29 MB
  __bf16* QKV = Wt + (size_t)3072 * 1024;        // [8192,3072]  50.33 MB
  __bf16* Xb = QKV + (size_t)8192 * 3072;        // [8192,1024]  16.78 MB
  __bf16* Vtr = Xb;                              // aliases Xb (dead after GEMM)

  convert_x<<<8192, 256, 0, stream>>>(x, Xb);
  transpose_w<<<dim3(48, 16), 256, 0, stream>>>(w, Wt);
  gemm_qkv<<<dim3(24, 64), 256, 0, stream>>>(Xb, Wt, QKV);
  transpose_v<<<dim3(32, 16, 4), 256, 0, stream>>>(QKV, Vtr);
  attn<<<dim3(8, 16, 4), 256, 0, stream>>>(QKV, Vtr, out);
}

// Round 6
// 253.917 us; speedup vs baseline: 1.1308x; 1.1308x over previous
//
#include <hip/hip_runtime.h>
#include <hip/hip_bf16.h>
#include <math.h>

typedef __bf16 bf16x4 __attribute__((ext_vector_type(4)));
typedef __bf16 bf16x8 __attribute__((ext_vector_type(8)));
typedef float f32x4 __attribute__((ext_vector_type(4)));

#define MFMA16(a, b, c) __builtin_amdgcn_mfma_f32_16x16x32_bf16(a, b, c, 0, 0, 0)
#define QSCALE 0.1803368801111204f  // 0.125 * log2(e): folded into W's Q-columns

// async global->LDS, 16B/lane, dest = wave-uniform base + lane*16
__device__ __forceinline__ void gload_lds16(const __bf16* g, __bf16* l) {
  __builtin_amdgcn_global_load_lds((const __attribute__((address_space(1))) void*)g,
                                   (__attribute__((address_space(3))) void*)l,
                                   16, 0, 0);
}

// ---------------------------------------------------------------------------
// Kernel 0: convert X fp32 -> bf16
// ---------------------------------------------------------------------------
__global__ __launch_bounds__(256) void convert_x(const float* __restrict__ in,
                                                 __bf16* __restrict__ out) {
  int i = blockIdx.x * 256 + threadIdx.x;
  float4 v = ((const float4*)in)[i];
  bf16x4 o = {(__bf16)v.x, (__bf16)v.y, (__bf16)v.z, (__bf16)v.w};
  *(bf16x4*)&out[i * 4] = o;
}

// ---------------------------------------------------------------------------
// Kernel 1: transpose+convert W fp32 [1024,3072] -> Wt bf16 [3072,1024].
//   Q output-features (bx<16) pre-scaled by 0.125*log2(e): softmax exp
//   becomes a bare v_exp_f32 in attn.
// ---------------------------------------------------------------------------
__global__ __launch_bounds__(256) void transpose_w(const float* __restrict__ W,
                                                   __bf16* __restrict__ Wt) {
  __shared__ __bf16 tile[64][65];
  const int bx = blockIdx.x;
  const int by = blockIdx.y;
  const int t = threadIdx.x;
  const int lr = t >> 6;
  const int lc = t & 63;
  const float sc = (bx < 16) ? QSCALE : 1.0f;  // block-uniform
#pragma unroll
  for (int i = 0; i < 16; ++i) {
    int r = lr + i * 4;
    tile[r][lc] = (__bf16)(W[(size_t)(by * 64 + r) * 3072 + bx * 64 + lc] * sc);
  }
  __syncthreads();
#pragma unroll
  for (int i = 0; i < 16; ++i) {
    int r = lr + i * 4;
    Wt[(size_t)(bx * 64 + r) * 1024 + by * 64 + lc] = tile[lc][r];
  }
}

// ---------------------------------------------------------------------------
// Kernel 2: QKV = X @ W. 128x128 tile, BK=32, global_load_lds width=16
//   (m97 ladder structure: unpadded LDS [row][32], 2-barrier K-loop).
// ---------------------------------------------------------------------------
__global__ __launch_bounds__(256) void gemm_qkv(const __bf16* __restrict__ X,
                                                const __bf16* __restrict__ Wt,
                                                __bf16* __restrict__ QKV) {
  __shared__ __bf16 As[128 * 32];
  __shared__ __bf16 Bs[128 * 32];
  const int t = threadIdx.x;
  const int lane = t & 63;
  const int wave = t >> 6;
  const int quad = lane >> 4;
  const int l16 = lane & 15;
  const int n0 = blockIdx.x * 128;
  const int m0 = blockIdx.y * 128;
  const int wm = (wave & 1) * 64;
  const int wn = (wave >> 1) * 64;

  const __bf16* Ag = &X[(size_t)(m0 + wave * 16 + (lane >> 2)) * 1024 + (lane & 3) * 8];
  const __bf16* Bg = &Wt[(size_t)(n0 + wave * 16 + (lane >> 2)) * 1024 + (lane & 3) * 8];
  __bf16* As0 = &As[wave * 512];
  __bf16* As1 = &As[2048 + wave * 512];
  __bf16* Bs0 = &Bs[wave * 512];
  __bf16* Bs1 = &Bs[2048 + wave * 512];

  f32x4 acc[4][4] = {};

  for (int k0 = 0; k0 < 1024; k0 += 32) {
    gload_lds16(Ag + k0, As0);
    gload_lds16(Ag + (size_t)64 * 1024 + k0, As1);
    gload_lds16(Bg + k0, Bs0);
    gload_lds16(Bg + (size_t)64 * 1024 + k0, Bs1);
    __syncthreads();

    bf16x8 af[4], bf[4];
#pragma unroll
    for (int mi = 0; mi < 4; ++mi)
      af[mi] = *(const bf16x8*)&As[(wm + mi * 16 + l16) * 32 + quad * 8];
#pragma unroll
    for (int ni = 0; ni < 4; ++ni)
      bf[ni] = *(const bf16x8*)&Bs[(wn + ni * 16 + l16) * 32 + quad * 8];
#pragma unroll
    for (int mi = 0; mi < 4; ++mi)
#pragma unroll
      for (int ni = 0; ni < 4; ++ni)
        acc[mi][ni] = MFMA16(af[mi], bf[ni], acc[mi][ni]);
    __syncthreads();
  }

#pragma unroll
  for (int mi = 0; mi < 4; ++mi)
#pragma unroll
    for (int ni = 0; ni < 4; ++ni)
#pragma unroll
      for (int r = 0; r < 4; ++r) {
        int row = m0 + wm + mi * 16 + quad * 4 + r;
        int col = n0 + wn + ni * 16 + l16;
        QKV[(size_t)row * 3072 + col] = (__bf16)acc[mi][ni][r];
      }
}

// ---------------------------------------------------------------------------
// Kernel 3: transpose V part of QKV -> Vt [b*16+h][d=64][key=2048]  bf16
// ---------------------------------------------------------------------------
__global__ __launch_bounds__(256) void transpose_v(const __bf16* __restrict__ QKV,
                                                   __bf16* __restrict__ Vt) {
  __shared__ __bf16 tile[64][65];
  const int k0 = blockIdx.x * 64;
  const int h = blockIdx.y;
  const int b = blockIdx.z;
  const int t = threadIdx.x;
  const int lr = t >> 6;
  const int lc = t & 63;
  const __bf16* src = QKV + (size_t)b * 2048 * 3072 + 2048 + h * 64;
  __bf16* dst = Vt + (size_t)(b * 16 + h) * 64 * 2048;
#pragma unroll
  for (int i = 0; i < 16; ++i) {
    int r = lr + i * 4;
    tile[r][lc] = src[(size_t)(k0 + r) * 3072 + lc];
  }
  __syncthreads();
#pragma unroll
  for (int i = 0; i < 16; ++i) {
    int d = lr + i * 4;
    dst[(size_t)d * 2048 + k0 + lc] = tile[lc][d];
  }
}

// ---------------------------------------------------------------------------
// Kernel 4: flash attention — round-4 shape (32 q/wave, 72 VGPR, 4 blk/CU)
//   + round-5 softmax (pre-folded scale, bare v_exp_f32, per-mt fusion).
//   Block = 128 q-rows of one (b,h); 4 waves x 32 q-rows; 32 KV tiles of 64.
// ---------------------------------------------------------------------------
#define AT_LD 72  // 144B = 9 x 16B rows: b128 frag reads balanced across superbanks

__global__ __launch_bounds__(256) void attn(const __bf16* __restrict__ QKV,
                                            const __bf16* __restrict__ Vt,
                                            float* __restrict__ Out) {
  const int h = blockIdx.y;
  const int b = blockIdx.z;
  const int t = threadIdx.x;
  const int lane = t & 63;
  const int wave = t >> 6;
  const int quad = lane >> 4;
  const int l16 = lane & 15;
  const int q0w = blockIdx.x * 128 + wave * 32;

  const size_t base = (size_t)b * 2048 * 3072;
  const __bf16* Qb = QKV + base + h * 64;
  const __bf16* Kb = QKV + base + 1024 + h * 64;
  const __bf16* Vtb = Vt + (size_t)(b * 16 + h) * 64 * 2048;  // [d][key]

  __shared__ __bf16 Ks[64 * AT_LD];     // [key][d]
  __shared__ __bf16 Vs[64 * AT_LD];     // [d][key]
  __shared__ __bf16 Ps[4][32 * AT_LD];  // wave-private [q][key]
  __bf16* Psw = Ps[wave];

  // Q fragments: lane holds Q[q=mi*16+l16][d=kc*32+quad*8+j]  (pre-scaled)
  bf16x8 qf[2][2];
#pragma unroll
  for (int mi = 0; mi < 2; ++mi)
#pragma unroll
    for (int kc = 0; kc < 2; ++kc)
      qf[mi][kc] = *(const bf16x8*)&Qb[(size_t)(q0w + mi * 16 + l16) * 3072 + kc * 32 + quad * 8];

  f32x4 o[2][4] = {};
  float lsum[2] = {0.0f, 0.0f};

  const int srow = t >> 2;      // staging row 0..63
  const int sc = (t & 3) * 16;  // staging col chunk

  for (int kv0 = 0; kv0 < 2048; kv0 += 64) {
    // ---- stage K [key][d] and V [d][key] (coalesced, reg round-trip) ----
    bf16x8 k0v = *(const bf16x8*)&Kb[(size_t)(kv0 + srow) * 3072 + sc];
    bf16x8 k1v = *(const bf16x8*)&Kb[(size_t)(kv0 + srow) * 3072 + sc + 8];
    bf16x8 v0v = *(const bf16x8*)&Vtb[(size_t)srow * 2048 + kv0 + sc];
    bf16x8 v1v = *(const bf16x8*)&Vtb[(size_t)srow * 2048 + kv0 + sc + 8];
    __syncthreads();  // prior tile's fragment reads done
    *(bf16x8*)&Ks[srow * AT_LD + sc] = k0v;
    *(bf16x8*)&Ks[srow * AT_LD + sc + 8] = k1v;
    *(bf16x8*)&Vs[srow * AT_LD + sc] = v0v;
    *(bf16x8*)&Vs[srow * AT_LD + sc + 8] = v1v;
    __syncthreads();

    // ---- per key-tile mt: S^T = K.Q^T, immediate exp2 + P stash ----
#pragma unroll
    for (int mt = 0; mt < 4; ++mt) {
      bf16x8 kf0 = *(const bf16x8*)&Ks[(mt * 16 + l16) * AT_LD + quad * 8];
      bf16x8 kf1 = *(const bf16x8*)&Ks[(mt * 16 + l16) * AT_LD + 32 + quad * 8];
#pragma unroll
      for (int mi = 0; mi < 2; ++mi) {
        f32x4 z = {};
        z = MFMA16(kf0, qf[mi][0], z);
        z = MFMA16(kf1, qf[mi][1], z);
        // lane owns (q=l16, keys mt*16+quad*4+r); p = 2^z == e^(qk/8)
        bf16x4 pk;
#pragma unroll
        for (int r = 0; r < 4; ++r) {
          float p = __builtin_amdgcn_exp2f(z[r]);
          lsum[mi] += p;
          pk[r] = (__bf16)p;
        }
        *(bf16x4*)&Psw[(mi * 16 + l16) * AT_LD + mt * 16 + quad * 4] = pk;
      }
    }

    // ---- P A-fragments (wave-local, lgkmcnt-only dependency) ----
    bf16x8 pf[2][2];
#pragma unroll
    for (int mi = 0; mi < 2; ++mi)
#pragma unroll
      for (int kc = 0; kc < 2; ++kc)
        pf[mi][kc] = *(const bf16x8*)&Psw[(mi * 16 + l16) * AT_LD + kc * 32 + quad * 8];

    // ---- O += P V : 32q x 64d ----
#pragma unroll
    for (int dt = 0; dt < 4; ++dt) {
      bf16x8 vf0 = *(const bf16x8*)&Vs[(dt * 16 + l16) * AT_LD + quad * 8];
      bf16x8 vf1 = *(const bf16x8*)&Vs[(dt * 16 + l16) * AT_LD + 32 + quad * 8];
#pragma unroll
      for (int mi = 0; mi < 2; ++mi) {
        o[mi][dt] = MFMA16(pf[mi][0], vf0, o[mi][dt]);
        o[mi][dt] = MFMA16(pf[mi][1], vf1, o[mi][dt]);
      }
    }
  }

  // ---- denominator: combine the 4 quads' key-partitions ----
#pragma unroll
  for (int mi = 0; mi < 2; ++mi) {
    lsum[mi] += __shfl_xor(lsum[mi], 16);
    lsum[mi] += __shfl_xor(lsum[mi], 32);
  }

  // ---- epilogue ----
#pragma unroll
  for (int mi = 0; mi < 2; ++mi)
#pragma unroll
    for (int r = 0; r < 4; ++r) {
      float inv = 1.0f / __shfl(lsum[mi], quad * 4 + r);
      int orow = b * 2048 + q0w + mi * 16 + quad * 4 + r;
#pragma unroll
      for (int dt = 0; dt < 4; ++dt)
        Out[(size_t)orow * 1024 + h * 64 + dt * 16 + l16] = o[mi][dt][r] * inv;
    }
}

// ---------------------------------------------------------------------------
extern "C" void kernel_launch(void* const* d_in, const int* in_sizes, int n_in,
                              void* d_out, int out_size, void* d_ws, size_t ws_size,
                              hipStream_t stream) {
  const float* x = (const float*)d_in[0];        // [4,2048,1024] fp32
  const float* w = (const float*)d_in[1];        // [1024,3072]  fp32
  float* out = (float*)d_out;                    // [4,2048,1024] fp32

  __bf16* Wt = (__bf16*)d_ws;                    // [3072,1024]   6.29 MB
  __bf16* QKV = Wt + (size_t)3072 * 1024;        // [8192,3072]  50.33 MB
  __bf16* Xb = QKV + (size_t)8192 * 3072;        // [8192,1024]  16.78 MB
  __bf16* Vtr = Xb;                              // aliases Xb (dead after GEMM)

  convert_x<<<8192, 256, 0, stream>>>(x, Xb);
  transpose_w<<<dim3(48, 16), 256, 0, stream>>>(w, Wt);
  gemm_qkv<<<dim3(24, 64), 256, 0, stream>>>(Xb, Wt, QKV);
  transpose_v<<<dim3(32, 16, 4), 256, 0, stream>>>(QKV, Vtr);
  attn<<<dim3(16, 16, 4), 256, 0, stream>>>(QKV, Vtr, out);
}